// Round 5
// baseline (324.779 us; speedup 1.0000x reference)
//
#include <hip/hip_runtime.h>

#define Bn 2
#define Nn 384
#define Dn 256
#define Rn 128
#define Sn 64
#define BNn (Bn*Nn)
#define NEG_LOG2E -1.44269504088896f

typedef short short8 __attribute__((ext_vector_type(8)));
typedef float f32x4 __attribute__((ext_vector_type(4)));
typedef unsigned int uint;
typedef unsigned short ushort;

static __device__ __forceinline__ float fast_sigmoid(float x) {
    return __builtin_amdgcn_rcpf(1.0f + __expf(-x));
}
static __device__ __forceinline__ ushort f2bf(float f) {
    uint u = __float_as_uint(f);
    uint r = (u + 0x7fffu + ((u >> 16) & 1u)) >> 16;   // RNE
    return (ushort)r;
}
static __device__ __forceinline__ float bf2f(ushort u) {
    return __uint_as_float(((uint)u) << 16);
}

// ================= K1: prep = zero-stats + projections + VdT transpose =================
// grid 320 x 256. Blocks 0..191: proj of 4 t-rows each. Blocks 192..319: VdT prep.
__global__ __launch_bounds__(256)
void prep_kernel(const float* __restrict__ t,
                 const float* __restrict__ Qd, const float* __restrict__ Kd,
                 const float* __restrict__ Vd,
                 const float* __restrict__ Qs, const float* __restrict__ Ks,
                 float* __restrict__ q, float* __restrict__ k,
                 ushort* __restrict__ qdb, ushort* __restrict__ kdb,
                 ushort* __restrict__ VdT, float* __restrict__ stats) {
    const int bi = blockIdx.x;
    const int tid = threadIdx.x;
    if (bi >= 192) {
        // VdT[d][r] = bf16(-log2(e) * Vd[r][d])  (pre-scaled for exp2-based gate)
        const int idx = (bi - 192) * 256 + tid;       // 0..32767
        const int d = idx >> 7, r = idx & 127;
        VdT[idx] = f2bf(NEG_LOG2E * Vd[(size_t)r * Dn + d]);
        if (bi == 319 && tid < 4) stats[tid] = 0.0f;
        return;
    }
    __shared__ float trow[4][Dn];
    const int r0 = bi * 4;
    for (int idx = tid; idx < 4 * Dn; idx += 256)
        trow[idx >> 8][idx & 255] = t[(size_t)r0 * Dn + idx];
    __syncthreads();
    // qd / kd (bf16): all 256 threads
    {
        const float* W = (tid < 128) ? Qd : Kd;
        ushort* ob = (tid < 128) ? qdb : kdb;
        const int col = tid & 127;
        float a0 = 0.f, a1 = 0.f, a2 = 0.f, a3 = 0.f;
        for (int kk = 0; kk < Dn; kk += 4) {
            float4 t0 = *(const float4*)&trow[0][kk];
            float4 t1 = *(const float4*)&trow[1][kk];
            float4 t2 = *(const float4*)&trow[2][kk];
            float4 t3 = *(const float4*)&trow[3][kk];
            float w0 = W[(size_t)(kk + 0) * 128 + col];
            float w1 = W[(size_t)(kk + 1) * 128 + col];
            float w2 = W[(size_t)(kk + 2) * 128 + col];
            float w3 = W[(size_t)(kk + 3) * 128 + col];
            a0 += t0.x * w0 + t0.y * w1 + t0.z * w2 + t0.w * w3;
            a1 += t1.x * w0 + t1.y * w1 + t1.z * w2 + t1.w * w3;
            a2 += t2.x * w0 + t2.y * w1 + t2.z * w2 + t2.w * w3;
            a3 += t3.x * w0 + t3.y * w1 + t3.z * w2 + t3.w * w3;
        }
        ob[(size_t)(r0 + 0) * 128 + col] = f2bf(a0);
        ob[(size_t)(r0 + 1) * 128 + col] = f2bf(a1);
        ob[(size_t)(r0 + 2) * 128 + col] = f2bf(a2);
        ob[(size_t)(r0 + 3) * 128 + col] = f2bf(a3);
    }
    // q / k (fp32): threads < 128
    if (tid < 128) {
        const float* W = (tid < 64) ? Qs : Ks;
        float* of = (tid < 64) ? q : k;
        const int col = tid & 63;
        float a0 = 0.f, a1 = 0.f, a2 = 0.f, a3 = 0.f;
        for (int kk = 0; kk < Dn; kk += 4) {
            float4 t0 = *(const float4*)&trow[0][kk];
            float4 t1 = *(const float4*)&trow[1][kk];
            float4 t2 = *(const float4*)&trow[2][kk];
            float4 t3 = *(const float4*)&trow[3][kk];
            float w0 = W[(size_t)(kk + 0) * 64 + col];
            float w1 = W[(size_t)(kk + 1) * 64 + col];
            float w2 = W[(size_t)(kk + 2) * 64 + col];
            float w3 = W[(size_t)(kk + 3) * 64 + col];
            a0 += t0.x * w0 + t0.y * w1 + t0.z * w2 + t0.w * w3;
            a1 += t1.x * w0 + t1.y * w1 + t1.z * w2 + t1.w * w3;
            a2 += t2.x * w0 + t2.y * w1 + t2.z * w2 + t2.w * w3;
            a3 += t3.x * w0 + t3.y * w1 + t3.z * w2 + t3.w * w3;
        }
        of[(size_t)(r0 + 0) * 64 + col] = a0;
        of[(size_t)(r0 + 1) * 64 + col] = a1;
        of[(size_t)(r0 + 2) * 64 + col] = a2;
        of[(size_t)(r0 + 3) * 64 + col] = a3;
    }
}

// ================= K2: s_sym + off-diag stats =================
__global__ __launch_bounds__(256)
void ssym_kernel(const float* __restrict__ q, const float* __restrict__ k,
                 float* __restrict__ ssym, float* __restrict__ stats) {
    __shared__ float qi[16][68], ki[16][68], qj[16][68], kj[16][68];
    __shared__ float red[256];
    const int b = blockIdx.z, it = blockIdx.x, jt = blockIdx.y;
    const int tid = threadIdx.x;
    const int r0 = tid >> 6, c = tid & 63;
#pragma unroll
    for (int p = 0; p < 4; ++p) {
        int row = r0 + 4 * p;
        qi[row][c] = q[((size_t)(b * Nn + it * 16 + row)) * Sn + c];
        ki[row][c] = k[((size_t)(b * Nn + it * 16 + row)) * Sn + c];
        qj[row][c] = q[((size_t)(b * Nn + jt * 16 + row)) * Sn + c];
        kj[row][c] = k[((size_t)(b * Nn + jt * 16 + row)) * Sn + c];
    }
    __syncthreads();
    const int ti = tid >> 4, tj = tid & 15;
    float acc = 0.0f;
#pragma unroll
    for (int dd = 0; dd < Sn; dd += 4) {
        float4 a  = *(const float4*)&qi[ti][dd];
        float4 bb = *(const float4*)&kj[tj][dd];
        float4 cc = *(const float4*)&qj[tj][dd];
        float4 d  = *(const float4*)&ki[ti][dd];
        acc += a.x * bb.x + a.y * bb.y + a.z * bb.z + a.w * bb.w
             + cc.x * d.x + cc.y * d.y + cc.z * d.z + cc.w * d.w;
    }
    const float sval = acc * 0.0625f;
    const int gi = it * 16 + ti, gj = jt * 16 + tj;
    ssym[((size_t)(b * Nn + gi)) * Nn + gj] = sval;
    const float v = (gi == gj) ? 0.0f : sval;

    red[tid] = v;
    __syncthreads();
    for (int off = 128; off > 0; off >>= 1) {
        if (tid < off) red[tid] += red[tid + off];
        __syncthreads();
    }
    const float tot_s = red[0];
    __syncthreads();
    red[tid] = v * v;
    __syncthreads();
    for (int off = 128; off > 0; off >>= 1) {
        if (tid < off) red[tid] += red[tid + off];
        __syncthreads();
    }
    if (tid == 0) {
        atomicAdd(&stats[b * 2 + 0], tot_s);
        atomicAdd(&stats[b * 2 + 1], red[0]);
    }
}

// ================= K3: m[row] + out init (out = t) =================
__global__ __launch_bounds__(256)
void m_kernel(const float* __restrict__ ssym, const float* __restrict__ stats,
              const float* __restrict__ a_l, const float* __restrict__ b_l,
              const float* __restrict__ t, float* __restrict__ out,
              float* __restrict__ m) {
    __shared__ float red[256];
    const int row = blockIdx.x;
    const int b = row / Nn;
    const float cnt_inv = 1.0f / (float)(Nn * (Nn - 1));
    const float mu = stats[b * 2 + 0] * cnt_inv;
    const float var = stats[b * 2 + 1] * cnt_inv - mu * mu;
    const float isg = rsqrtf(var + 1e-6f);
    const float a = a_l[0], bbias = b_l[0];
    const int tid = threadIdx.x;
    // out init: pair kernel atomically subtracts partials
    out[(size_t)row * Dn + tid] = t[(size_t)row * Dn + tid];
    float sum = __expf(a * (ssym[(size_t)row * Nn + tid] - mu) * isg + bbias);
    if (tid < 128)
        sum += __expf(a * (ssym[(size_t)row * Nn + 256 + tid] - mu) * isg + bbias);
    red[tid] = sum;
    __syncthreads();
    for (int off = 128; off > 0; off >>= 1) {
        if (tid < off) red[tid] += red[tid + off];
        __syncthreads();
    }
    if (tid == 0) m[row] = 1.0f / (red[0] + 1e-6f);
}

// ================= K4: pair kernel, j-split x3 =================
// Grid 3*BNn. Block (tile, bi): one (b,i), j in [tile*128, tile*128+128).
// acc = -log2e * (kappa_ij - kappa_ji)[d] via MFMA A(VdT d x r) * B(h r x j);
// gate = 1/(1+2^acc) = sigmoid(kappa_diff). Partial sums atomically subtracted
// from out (pre-initialized to t by m_kernel).
__global__ __launch_bounds__(256, 4)
void pair_kernel(const float* __restrict__ t, const float* __restrict__ ssym,
                 const float* __restrict__ mptr, const float* __restrict__ stats,
                 const float* __restrict__ a_l, const float* __restrict__ b_l,
                 const ushort* __restrict__ qdb, const ushort* __restrict__ kdb,
                 const ushort* __restrict__ VdT, float* __restrict__ out) {
    __shared__ ushort h_s[128][136];     // h[j_local][r] bf16, row pad 136
    __shared__ float alpha_s[Nn];
    __shared__ float qdi_s[Rn], kdi_s[Rn];
    __shared__ float red[256];

    const int bx = blockIdx.x;
    const int tile = bx >> 10 < 0 ? 0 : bx / BNn;     // 0..2
    const int bi = bx - tile * BNn;                   // 0..767
    const int jt0 = tile * 128;
    const int b = bi / Nn;
    const int i = bi - b * Nn;
    const int tid = threadIdx.x;
    const int wave = tid >> 6, lane = tid & 63;
    const int ln = lane & 15, quad = lane >> 4;
    const int wd0 = wave * 64;

    // ---- issue staging loads for this block's j-tile up front ----
    const int jj = tid >> 1;
    const int r0s = (tid & 1) * 64;
    const size_t rowj = (size_t)(b * Nn + jt0 + jj) * Rn;
    const uint4* qp = (const uint4*)(qdb + rowj + r0s);
    const uint4* kp = (const uint4*)(kdb + rowj + r0s);
    uint4 qv[8], kv[8];
#pragma unroll
    for (int c = 0; c < 8; ++c) { qv[c] = qp[c]; kv[c] = kp[c]; }

    if (tid < Rn) {
        qdi_s[tid] = bf2f(qdb[(size_t)bi * Rn + tid]);
        kdi_s[tid] = bf2f(kdb[(size_t)bi * Rn + tid]);
    }

    // ---- inline alpha row (full row; redundant across the 3 sibling blocks) ----
    {
        const float cnt_inv = 1.0f / (float)(Nn * (Nn - 1));
        const float mu = stats[b * 2 + 0] * cnt_inv;
        const float var = stats[b * 2 + 1] * cnt_inv - mu * mu;
        const float isg = rsqrtf(var + 1e-6f);
        const float a = a_l[0], bbias = b_l[0];
        float A0, am0, A1 = 0.f, am1 = 0.f;
        {
            float s0 = ssym[(size_t)bi * Nn + tid];
            A0 = fast_sigmoid(a * (s0 - mu) * isg + bbias);
            am0 = A0 * mptr[b * Nn + tid];
        }
        if (tid < 128) {
            float s1 = ssym[(size_t)bi * Nn + 256 + tid];
            A1 = fast_sigmoid(a * (s1 - mu) * isg + bbias);
            am1 = A1 * mptr[b * Nn + 256 + tid];
        }
        red[tid] = am0 + am1;
        __syncthreads();
        for (int off = 128; off > 0; off >>= 1) {
            if (tid < off) red[tid] += red[tid + off];
            __syncthreads();
        }
        const float inv = 1.0f / (red[0] + 1e-6f);
        alpha_s[tid] = (tid == i) ? 0.f : A0 * am0 * inv;
        if (tid < 128)
            alpha_s[256 + tid] = ((256 + tid) == i) ? 0.f : A1 * am1 * inv;
    }

    // ---- convert staged loads to h tile: h[j][r] = qd_i[r]*kd_j[r] - kd_i[r]*qd_j[r] ----
#pragma unroll
    for (int c = 0; c < 8; ++c) {
        uint pk[4];
#pragma unroll
        for (int p = 0; p < 4; ++p) {
            uint qu = (&qv[c].x)[p], ku = (&kv[c].x)[p];
            float qlo = __uint_as_float(qu << 16);
            float qhi = __uint_as_float(qu & 0xffff0000u);
            float klo = __uint_as_float(ku << 16);
            float khi = __uint_as_float(ku & 0xffff0000u);
            const int r = r0s + c * 8 + p * 2;
            float h0 = qdi_s[r]     * klo - kdi_s[r]     * qlo;
            float h1 = qdi_s[r + 1] * khi - kdi_s[r + 1] * qhi;
            pk[p] = (uint)f2bf(h0) | ((uint)f2bf(h1) << 16);
        }
        uint4 w; w.x = pk[0]; w.y = pk[1]; w.z = pk[2]; w.w = pk[3];
        *(uint4*)&h_s[jj][r0s + c * 8] = w;
    }

    // A-fragments of VdT (constant over j)
    short8 vf[4][4];
#pragma unroll
    for (int dt = 0; dt < 4; ++dt)
#pragma unroll
        for (int ks = 0; ks < 4; ++ks)
            vf[dt][ks] = *(const short8*)&VdT[(size_t)(wd0 + dt * 16 + ln) * Rn + ks * 32 + quad * 8];

    float4 tiv[4];
#pragma unroll
    for (int dt = 0; dt < 4; ++dt)
        tiv[dt] = *(const float4*)&t[(size_t)bi * Dn + wd0 + dt * 16 + quad * 4];

    float4 outac[4];
#pragma unroll
    for (int dt = 0; dt < 4; ++dt) outac[dt] = make_float4(0.f, 0.f, 0.f, 0.f);

    __syncthreads();   // h_s + alpha_s ready

    // ---- 8 jsubs with next-iteration prefetch of hf/tjv/alpha ----
    short8 hf_c[4];
    float4 tjv_c[4];
    float al_c;
    {
        const int j = jt0 + ln;
#pragma unroll
        for (int ks = 0; ks < 4; ++ks)
            hf_c[ks] = *(const short8*)&h_s[ln][ks * 32 + quad * 8];
        al_c = alpha_s[j];
        const size_t trow_ = (size_t)(b * Nn + j) * Dn;
#pragma unroll
        for (int dt = 0; dt < 4; ++dt)
            tjv_c[dt] = *(const float4*)&t[trow_ + wd0 + dt * 16 + quad * 4];
    }

#pragma unroll 1
    for (int jsub = 0; jsub < 8; ++jsub) {
        short8 hf_n[4];
        float4 tjv_n[4];
        float al_n = 0.f;
        if (jsub < 7) {
            const int jn = jt0 + (jsub + 1) * 16 + ln;
#pragma unroll
            for (int ks = 0; ks < 4; ++ks)
                hf_n[ks] = *(const short8*)&h_s[(jsub + 1) * 16 + ln][ks * 32 + quad * 8];
            al_n = alpha_s[jn];
            const size_t trow_ = (size_t)(b * Nn + jn) * Dn;
#pragma unroll
            for (int dt = 0; dt < 4; ++dt)
                tjv_n[dt] = *(const float4*)&t[trow_ + wd0 + dt * 16 + quad * 4];
        }

        f32x4 aA[4], aB[4];
#pragma unroll
        for (int dt = 0; dt < 4; ++dt) {
            f32x4 x = {0.f, 0.f, 0.f, 0.f}, y = {0.f, 0.f, 0.f, 0.f};
            x = __builtin_amdgcn_mfma_f32_16x16x32_bf16(vf[dt][0], hf_c[0], x, 0, 0, 0);
            y = __builtin_amdgcn_mfma_f32_16x16x32_bf16(vf[dt][1], hf_c[1], y, 0, 0, 0);
            x = __builtin_amdgcn_mfma_f32_16x16x32_bf16(vf[dt][2], hf_c[2], x, 0, 0, 0);
            y = __builtin_amdgcn_mfma_f32_16x16x32_bf16(vf[dt][3], hf_c[3], y, 0, 0, 0);
            aA[dt] = x; aB[dt] = y;
        }
#pragma unroll
        for (int dt = 0; dt < 4; ++dt) {
            const float4 tj = tjv_c[dt];
            float e0 = aA[dt][0] + aB[dt][0];
            float e1 = aA[dt][1] + aB[dt][1];
            float e2 = aA[dt][2] + aB[dt][2];
            float e3 = aA[dt][3] + aB[dt][3];
            float g0 = __builtin_amdgcn_rcpf(1.0f + __builtin_amdgcn_exp2f(e0));
            float g1 = __builtin_amdgcn_rcpf(1.0f + __builtin_amdgcn_exp2f(e1));
            float g2 = __builtin_amdgcn_rcpf(1.0f + __builtin_amdgcn_exp2f(e2));
            float g3 = __builtin_amdgcn_rcpf(1.0f + __builtin_amdgcn_exp2f(e3));
            outac[dt].x += al_c * g0 * (tiv[dt].x - tj.x);
            outac[dt].y += al_c * g1 * (tiv[dt].y - tj.y);
            outac[dt].z += al_c * g2 * (tiv[dt].z - tj.z);
            outac[dt].w += al_c * g3 * (tiv[dt].w - tj.w);
        }
#pragma unroll
        for (int ks = 0; ks < 4; ++ks) hf_c[ks] = hf_n[ks];
#pragma unroll
        for (int dt = 0; dt < 4; ++dt) tjv_c[dt] = tjv_n[dt];
        al_c = al_n;
    }

    // ---- reduce over the 16 j-lanes, atomically subtract partial from out ----
#pragma unroll
    for (int dt = 0; dt < 4; ++dt) {
        float4 v = outac[dt];
#pragma unroll
        for (int mask = 1; mask < 16; mask <<= 1) {
            v.x += __shfl_xor(v.x, mask);
            v.y += __shfl_xor(v.y, mask);
            v.z += __shfl_xor(v.z, mask);
            v.w += __shfl_xor(v.w, mask);
        }
        if (ln == 0) {
            float* op = &out[(size_t)bi * Dn + wd0 + dt * 16 + quad * 4];
            atomicAdd(op + 0, -v.x);
            atomicAdd(op + 1, -v.y);
            atomicAdd(op + 2, -v.z);
            atomicAdd(op + 3, -v.w);
        }
    }
}

extern "C" void kernel_launch(void* const* d_in, const int* in_sizes, int n_in,
                              void* d_out, int out_size, void* d_ws, size_t ws_size,
                              hipStream_t stream) {
    const float* t   = (const float*)d_in[0];
    const float* Qd  = (const float*)d_in[1];
    const float* Kd  = (const float*)d_in[2];
    const float* Vd  = (const float*)d_in[3];
    const float* Qs  = (const float*)d_in[4];
    const float* Ks  = (const float*)d_in[5];
    const float* a_l = (const float*)d_in[6];
    const float* b_l = (const float*)d_in[7];
    float* out = (float*)d_out;
    float* ws  = (float*)d_ws;

    float* q     = ws;                          // 768*64
    float* k     = q + BNn * Sn;                // 768*64
    float* ssym  = k + BNn * Sn;                // 768*384
    float* m     = ssym + (size_t)BNn * Nn;     // 768
    float* stats = m + BNn;                     // 8
    ushort* qdb  = (ushort*)(stats + 8);        // 768*128 bf16
    ushort* kdb  = qdb + (size_t)BNn * Rn;      // 768*128 bf16
    ushort* VdT  = kdb + (size_t)BNn * Rn;      // 256*128 bf16 (pre-scaled by -log2e)

    hipLaunchKernelGGL(prep_kernel, dim3(320), dim3(256), 0, stream,
                       t, Qd, Kd, Vd, Qs, Ks, q, k, qdb, kdb, VdT, stats);
    hipLaunchKernelGGL(ssym_kernel, dim3(Nn / 16, Nn / 16, Bn), dim3(256), 0, stream,
                       q, k, ssym, stats);
    hipLaunchKernelGGL(m_kernel, dim3(BNn), dim3(256), 0, stream,
                       ssym, stats, a_l, b_l, t, out, m);
    hipLaunchKernelGGL(pair_kernel, dim3(3 * BNn), dim3(256), 0, stream,
                       t, ssym, m, stats, a_l, b_l, qdb, kdb, VdT, out);
}

// Round 6
// 191.854 us; speedup vs baseline: 1.6928x; 1.6928x over previous
//
#include <hip/hip_runtime.h>

#define Bn 2
#define Nn 384
#define Dn 256
#define Rn 128
#define Sn 64
#define BNn (Bn*Nn)
#define NEG_LOG2E -1.44269504088896f

typedef short short8 __attribute__((ext_vector_type(8)));
typedef float f32x4 __attribute__((ext_vector_type(4)));
typedef unsigned int uint;
typedef unsigned short ushort;

static __device__ __forceinline__ float fast_sigmoid(float x) {
    return __builtin_amdgcn_rcpf(1.0f + __expf(-x));
}
static __device__ __forceinline__ ushort f2bf(float f) {
    uint u = __float_as_uint(f);
    uint r = (u + 0x7fffu + ((u >> 16) & 1u)) >> 16;   // RNE
    return (ushort)r;
}
static __device__ __forceinline__ float bf2f(ushort u) {
    return __uint_as_float(((uint)u) << 16);
}

// ================= K1: prep = zero-stats + projections + VdT transpose =================
// grid 320 x 256. Blocks 0..191: proj of 4 t-rows each. Blocks 192..319: VdT prep.
__global__ __launch_bounds__(256)
void prep_kernel(const float* __restrict__ t,
                 const float* __restrict__ Qd, const float* __restrict__ Kd,
                 const float* __restrict__ Vd,
                 const float* __restrict__ Qs, const float* __restrict__ Ks,
                 float* __restrict__ q, float* __restrict__ k,
                 ushort* __restrict__ qdb, ushort* __restrict__ kdb,
                 ushort* __restrict__ VdT, float* __restrict__ stats) {
    const int bi = blockIdx.x;
    const int tid = threadIdx.x;
    if (bi >= 192) {
        // VdT[d][r] = bf16(-log2(e) * Vd[r][d])  (pre-scaled for exp2-based gate)
        const int idx = (bi - 192) * 256 + tid;       // 0..32767
        const int d = idx >> 7, r = idx & 127;
        VdT[idx] = f2bf(NEG_LOG2E * Vd[(size_t)r * Dn + d]);
        if (bi == 319 && tid < 4) stats[tid] = 0.0f;
        return;
    }
    __shared__ float trow[4][Dn];
    const int r0 = bi * 4;
    for (int idx = tid; idx < 4 * Dn; idx += 256)
        trow[idx >> 8][idx & 255] = t[(size_t)r0 * Dn + idx];
    __syncthreads();
    // qd / kd (bf16): all 256 threads
    {
        const float* W = (tid < 128) ? Qd : Kd;
        ushort* ob = (tid < 128) ? qdb : kdb;
        const int col = tid & 127;
        float a0 = 0.f, a1 = 0.f, a2 = 0.f, a3 = 0.f;
        for (int kk = 0; kk < Dn; kk += 4) {
            float4 t0 = *(const float4*)&trow[0][kk];
            float4 t1 = *(const float4*)&trow[1][kk];
            float4 t2 = *(const float4*)&trow[2][kk];
            float4 t3 = *(const float4*)&trow[3][kk];
            float w0 = W[(size_t)(kk + 0) * 128 + col];
            float w1 = W[(size_t)(kk + 1) * 128 + col];
            float w2 = W[(size_t)(kk + 2) * 128 + col];
            float w3 = W[(size_t)(kk + 3) * 128 + col];
            a0 += t0.x * w0 + t0.y * w1 + t0.z * w2 + t0.w * w3;
            a1 += t1.x * w0 + t1.y * w1 + t1.z * w2 + t1.w * w3;
            a2 += t2.x * w0 + t2.y * w1 + t2.z * w2 + t2.w * w3;
            a3 += t3.x * w0 + t3.y * w1 + t3.z * w2 + t3.w * w3;
        }
        ob[(size_t)(r0 + 0) * 128 + col] = f2bf(a0);
        ob[(size_t)(r0 + 1) * 128 + col] = f2bf(a1);
        ob[(size_t)(r0 + 2) * 128 + col] = f2bf(a2);
        ob[(size_t)(r0 + 3) * 128 + col] = f2bf(a3);
    }
    // q / k (fp32): threads < 128
    if (tid < 128) {
        const float* W = (tid < 64) ? Qs : Ks;
        float* of = (tid < 64) ? q : k;
        const int col = tid & 63;
        float a0 = 0.f, a1 = 0.f, a2 = 0.f, a3 = 0.f;
        for (int kk = 0; kk < Dn; kk += 4) {
            float4 t0 = *(const float4*)&trow[0][kk];
            float4 t1 = *(const float4*)&trow[1][kk];
            float4 t2 = *(const float4*)&trow[2][kk];
            float4 t3 = *(const float4*)&trow[3][kk];
            float w0 = W[(size_t)(kk + 0) * 64 + col];
            float w1 = W[(size_t)(kk + 1) * 64 + col];
            float w2 = W[(size_t)(kk + 2) * 64 + col];
            float w3 = W[(size_t)(kk + 3) * 64 + col];
            a0 += t0.x * w0 + t0.y * w1 + t0.z * w2 + t0.w * w3;
            a1 += t1.x * w0 + t1.y * w1 + t1.z * w2 + t1.w * w3;
            a2 += t2.x * w0 + t2.y * w1 + t2.z * w2 + t2.w * w3;
            a3 += t3.x * w0 + t3.y * w1 + t3.z * w2 + t3.w * w3;
        }
        of[(size_t)(r0 + 0) * 64 + col] = a0;
        of[(size_t)(r0 + 1) * 64 + col] = a1;
        of[(size_t)(r0 + 2) * 64 + col] = a2;
        of[(size_t)(r0 + 3) * 64 + col] = a3;
    }
}

// ================= K2: s_sym + off-diag stats =================
__global__ __launch_bounds__(256)
void ssym_kernel(const float* __restrict__ q, const float* __restrict__ k,
                 float* __restrict__ ssym, float* __restrict__ stats) {
    __shared__ float qi[16][68], ki[16][68], qj[16][68], kj[16][68];
    __shared__ float red[256];
    const int b = blockIdx.z, it = blockIdx.x, jt = blockIdx.y;
    const int tid = threadIdx.x;
    const int r0 = tid >> 6, c = tid & 63;
#pragma unroll
    for (int p = 0; p < 4; ++p) {
        int row = r0 + 4 * p;
        qi[row][c] = q[((size_t)(b * Nn + it * 16 + row)) * Sn + c];
        ki[row][c] = k[((size_t)(b * Nn + it * 16 + row)) * Sn + c];
        qj[row][c] = q[((size_t)(b * Nn + jt * 16 + row)) * Sn + c];
        kj[row][c] = k[((size_t)(b * Nn + jt * 16 + row)) * Sn + c];
    }
    __syncthreads();
    const int ti = tid >> 4, tj = tid & 15;
    float acc = 0.0f;
#pragma unroll
    for (int dd = 0; dd < Sn; dd += 4) {
        float4 a  = *(const float4*)&qi[ti][dd];
        float4 bb = *(const float4*)&kj[tj][dd];
        float4 cc = *(const float4*)&qj[tj][dd];
        float4 d  = *(const float4*)&ki[ti][dd];
        acc += a.x * bb.x + a.y * bb.y + a.z * bb.z + a.w * bb.w
             + cc.x * d.x + cc.y * d.y + cc.z * d.z + cc.w * d.w;
    }
    const float sval = acc * 0.0625f;
    const int gi = it * 16 + ti, gj = jt * 16 + tj;
    ssym[((size_t)(b * Nn + gi)) * Nn + gj] = sval;
    const float v = (gi == gj) ? 0.0f : sval;

    red[tid] = v;
    __syncthreads();
    for (int off = 128; off > 0; off >>= 1) {
        if (tid < off) red[tid] += red[tid + off];
        __syncthreads();
    }
    const float tot_s = red[0];
    __syncthreads();
    red[tid] = v * v;
    __syncthreads();
    for (int off = 128; off > 0; off >>= 1) {
        if (tid < off) red[tid] += red[tid + off];
        __syncthreads();
    }
    if (tid == 0) {
        atomicAdd(&stats[b * 2 + 0], tot_s);
        atomicAdd(&stats[b * 2 + 1], red[0]);
    }
}

// ================= K3: m[row] + out init (out = t) =================
__global__ __launch_bounds__(256)
void m_kernel(const float* __restrict__ ssym, const float* __restrict__ stats,
              const float* __restrict__ a_l, const float* __restrict__ b_l,
              const float* __restrict__ t, float* __restrict__ out,
              float* __restrict__ m) {
    __shared__ float red[256];
    const int row = blockIdx.x;
    const int b = row / Nn;
    const float cnt_inv = 1.0f / (float)(Nn * (Nn - 1));
    const float mu = stats[b * 2 + 0] * cnt_inv;
    const float var = stats[b * 2 + 1] * cnt_inv - mu * mu;
    const float isg = rsqrtf(var + 1e-6f);
    const float a = a_l[0], bbias = b_l[0];
    const int tid = threadIdx.x;
    // out init: pair kernel atomically subtracts partials
    out[(size_t)row * Dn + tid] = t[(size_t)row * Dn + tid];
    float sum = __expf(a * (ssym[(size_t)row * Nn + tid] - mu) * isg + bbias);
    if (tid < 128)
        sum += __expf(a * (ssym[(size_t)row * Nn + 256 + tid] - mu) * isg + bbias);
    red[tid] = sum;
    __syncthreads();
    for (int off = 128; off > 0; off >>= 1) {
        if (tid < off) red[tid] += red[tid + off];
        __syncthreads();
    }
    if (tid == 0) m[row] = 1.0f / (red[0] + 1e-6f);
}

// ================= K4: pair kernel, j-split x3, register-lean =================
// Grid 3*BNn, bx = tile*BNn + bi. Block handles (b,i), j in [tile*128, +128).
// acc = -log2e * (kappa_ij - kappa_ji)[d] via MFMA A(VdT d x r) * B(h r x j);
// gate = 1/(1+2^acc) = sigmoid(kappa_diff). Partials atomically subtracted
// from out (pre-initialized to t by m_kernel).
// NOTE: launch_bounds (256,3) is the known-good setting (R4: 84 VGPR, no spill).
// (256,4) in R5 forced VGPR=64 -> catastrophic scratch spill (FETCH 14->467 MB).
__global__ __launch_bounds__(256, 3)
void pair_kernel(const float* __restrict__ t, const float* __restrict__ ssym,
                 const float* __restrict__ mptr, const float* __restrict__ stats,
                 const float* __restrict__ a_l, const float* __restrict__ b_l,
                 const ushort* __restrict__ qdb, const ushort* __restrict__ kdb,
                 const ushort* __restrict__ VdT, float* __restrict__ out) {
    __shared__ ushort h_s[128][136];     // h[j_local][r] bf16, row pad 136 (16B-aligned rows)
    __shared__ float alpha_s[Nn];
    __shared__ float qdi_s[Rn], kdi_s[Rn];
    __shared__ float red[256];

    const int bx = blockIdx.x;
    const int tile = bx / BNn;                        // 0..2
    const int bi = bx - tile * BNn;                   // 0..767
    const int jt0 = tile * 128;
    const int b = bi / Nn;
    const int i = bi - b * Nn;
    const int tid = threadIdx.x;
    const int wave = tid >> 6, lane = tid & 63;
    const int ln = lane & 15, quad = lane >> 4;
    const int wd0 = wave * 64;

    if (tid < Rn) {
        qdi_s[tid] = bf2f(qdb[(size_t)bi * Rn + tid]);
        kdi_s[tid] = bf2f(kdb[(size_t)bi * Rn + tid]);
    }

    // ---- inline alpha row (full row; redundant across the 3 sibling blocks).
    // Its internal barriers also publish qdi_s/kdi_s for the h-build below. ----
    {
        const float cnt_inv = 1.0f / (float)(Nn * (Nn - 1));
        const float mu = stats[b * 2 + 0] * cnt_inv;
        const float var = stats[b * 2 + 1] * cnt_inv - mu * mu;
        const float isg = rsqrtf(var + 1e-6f);
        const float a = a_l[0], bbias = b_l[0];
        float A0, am0, A1 = 0.f, am1 = 0.f;
        {
            float s0 = ssym[(size_t)bi * Nn + tid];
            A0 = fast_sigmoid(a * (s0 - mu) * isg + bbias);
            am0 = A0 * mptr[b * Nn + tid];
        }
        if (tid < 128) {
            float s1 = ssym[(size_t)bi * Nn + 256 + tid];
            A1 = fast_sigmoid(a * (s1 - mu) * isg + bbias);
            am1 = A1 * mptr[b * Nn + 256 + tid];
        }
        red[tid] = am0 + am1;
        __syncthreads();
        for (int off = 128; off > 0; off >>= 1) {
            if (tid < off) red[tid] += red[tid + off];
            __syncthreads();
        }
        const float inv = 1.0f / (red[0] + 1e-6f);
        alpha_s[tid] = (tid == i) ? 0.f : A0 * am0 * inv;
        if (tid < 128)
            alpha_s[256 + tid] = ((256 + tid) == i) ? 0.f : A1 * am1 * inv;
    }

    // ---- stage h tile (transient registers only):
    //      h[j][r] = qd_i[r]*kd_j[r] - kd_i[r]*qd_j[r], bf16 ----
    {
        const int jj = tid >> 1;
        const int r0s = (tid & 1) * 64;
        const size_t rowj = (size_t)(b * Nn + jt0 + jj) * Rn;
        const uint4* qp = (const uint4*)(qdb + rowj + r0s);
        const uint4* kp = (const uint4*)(kdb + rowj + r0s);
#pragma unroll
        for (int c = 0; c < 8; ++c) {
            uint4 qv = qp[c], kv = kp[c];
            uint pk[4];
#pragma unroll
            for (int p = 0; p < 4; ++p) {
                uint qu = (&qv.x)[p], ku = (&kv.x)[p];
                float qlo = __uint_as_float(qu << 16);
                float qhi = __uint_as_float(qu & 0xffff0000u);
                float klo = __uint_as_float(ku << 16);
                float khi = __uint_as_float(ku & 0xffff0000u);
                const int r = r0s + c * 8 + p * 2;
                float h0 = qdi_s[r]     * klo - kdi_s[r]     * qlo;
                float h1 = qdi_s[r + 1] * khi - kdi_s[r + 1] * qhi;
                pk[p] = (uint)f2bf(h0) | ((uint)f2bf(h1) << 16);
            }
            uint4 w; w.x = pk[0]; w.y = pk[1]; w.z = pk[2]; w.w = pk[3];
            *(uint4*)&h_s[jj][r0s + c * 8] = w;
        }
    }

    // A-fragments of VdT (constant over j)
    short8 vf[4][4];
#pragma unroll
    for (int dt = 0; dt < 4; ++dt)
#pragma unroll
        for (int ks = 0; ks < 4; ++ks)
            vf[dt][ks] = *(const short8*)&VdT[(size_t)(wd0 + dt * 16 + ln) * Rn + ks * 32 + quad * 8];

    float4 tiv[4];
#pragma unroll
    for (int dt = 0; dt < 4; ++dt)
        tiv[dt] = *(const float4*)&t[(size_t)bi * Dn + wd0 + dt * 16 + quad * 4];

    float4 outac[4];
#pragma unroll
    for (int dt = 0; dt < 4; ++dt) outac[dt] = make_float4(0.f, 0.f, 0.f, 0.f);

    __syncthreads();   // h_s + alpha_s ready

    // ---- per 16-j subtile: MFMA (2 independent chains) + fused epilogue ----
#pragma unroll 1
    for (int jsub = 0; jsub < 8; ++jsub) {
        short8 hf[4];
#pragma unroll
        for (int ks = 0; ks < 4; ++ks)
            hf[ks] = *(const short8*)&h_s[jsub * 16 + ln][ks * 32 + quad * 8];
        const int j = jt0 + jsub * 16 + ln;
        const float al = alpha_s[j];
        const size_t trow_ = (size_t)(b * Nn + j) * Dn;
        float4 tjv[4];
#pragma unroll
        for (int dt = 0; dt < 4; ++dt)
            tjv[dt] = *(const float4*)&t[trow_ + wd0 + dt * 16 + quad * 4];

        f32x4 aA[4], aB[4];
#pragma unroll
        for (int dt = 0; dt < 4; ++dt) {
            f32x4 x = {0.f, 0.f, 0.f, 0.f}, y = {0.f, 0.f, 0.f, 0.f};
            x = __builtin_amdgcn_mfma_f32_16x16x32_bf16(vf[dt][0], hf[0], x, 0, 0, 0);
            y = __builtin_amdgcn_mfma_f32_16x16x32_bf16(vf[dt][1], hf[1], y, 0, 0, 0);
            x = __builtin_amdgcn_mfma_f32_16x16x32_bf16(vf[dt][2], hf[2], x, 0, 0, 0);
            y = __builtin_amdgcn_mfma_f32_16x16x32_bf16(vf[dt][3], hf[3], y, 0, 0, 0);
            aA[dt] = x; aB[dt] = y;
        }
#pragma unroll
        for (int dt = 0; dt < 4; ++dt) {
            const float4 tj = tjv[dt];
            float e0 = aA[dt][0] + aB[dt][0];
            float e1 = aA[dt][1] + aB[dt][1];
            float e2 = aA[dt][2] + aB[dt][2];
            float e3 = aA[dt][3] + aB[dt][3];
            float g0 = __builtin_amdgcn_rcpf(1.0f + __builtin_amdgcn_exp2f(e0));
            float g1 = __builtin_amdgcn_rcpf(1.0f + __builtin_amdgcn_exp2f(e1));
            float g2 = __builtin_amdgcn_rcpf(1.0f + __builtin_amdgcn_exp2f(e2));
            float g3 = __builtin_amdgcn_rcpf(1.0f + __builtin_amdgcn_exp2f(e3));
            outac[dt].x += al * g0 * (tiv[dt].x - tj.x);
            outac[dt].y += al * g1 * (tiv[dt].y - tj.y);
            outac[dt].z += al * g2 * (tiv[dt].z - tj.z);
            outac[dt].w += al * g3 * (tiv[dt].w - tj.w);
        }
    }

    // ---- reduce over the 16 j-lanes, atomically subtract partial from out ----
#pragma unroll
    for (int dt = 0; dt < 4; ++dt) {
        float4 v = outac[dt];
#pragma unroll
        for (int mask = 1; mask < 16; mask <<= 1) {
            v.x += __shfl_xor(v.x, mask);
            v.y += __shfl_xor(v.y, mask);
            v.z += __shfl_xor(v.z, mask);
            v.w += __shfl_xor(v.w, mask);
        }
        if (ln == 0) {
            float* op = &out[(size_t)bi * Dn + wd0 + dt * 16 + quad * 4];
            atomicAdd(op + 0, -v.x);
            atomicAdd(op + 1, -v.y);
            atomicAdd(op + 2, -v.z);
            atomicAdd(op + 3, -v.w);
        }
    }
}

extern "C" void kernel_launch(void* const* d_in, const int* in_sizes, int n_in,
                              void* d_out, int out_size, void* d_ws, size_t ws_size,
                              hipStream_t stream) {
    const float* t   = (const float*)d_in[0];
    const float* Qd  = (const float*)d_in[1];
    const float* Kd  = (const float*)d_in[2];
    const float* Vd  = (const float*)d_in[3];
    const float* Qs  = (const float*)d_in[4];
    const float* Ks  = (const float*)d_in[5];
    const float* a_l = (const float*)d_in[6];
    const float* b_l = (const float*)d_in[7];
    float* out = (float*)d_out;
    float* ws  = (float*)d_ws;

    float* q     = ws;                          // 768*64
    float* k     = q + BNn * Sn;                // 768*64
    float* ssym  = k + BNn * Sn;                // 768*384
    float* m     = ssym + (size_t)BNn * Nn;     // 768
    float* stats = m + BNn;                     // 8
    ushort* qdb  = (ushort*)(stats + 8);        // 768*128 bf16
    ushort* kdb  = qdb + (size_t)BNn * Rn;      // 768*128 bf16
    ushort* VdT  = kdb + (size_t)BNn * Rn;      // 256*128 bf16 (pre-scaled by -log2e)

    hipLaunchKernelGGL(prep_kernel, dim3(320), dim3(256), 0, stream,
                       t, Qd, Kd, Vd, Qs, Ks, q, k, qdb, kdb, VdT, stats);
    hipLaunchKernelGGL(ssym_kernel, dim3(Nn / 16, Nn / 16, Bn), dim3(256), 0, stream,
                       q, k, ssym, stats);
    hipLaunchKernelGGL(m_kernel, dim3(BNn), dim3(256), 0, stream,
                       ssym, stats, a_l, b_l, t, out, m);
    hipLaunchKernelGGL(pair_kernel, dim3(3 * BNn), dim3(256), 0, stream,
                       t, ssym, m, stats, a_l, b_l, qdb, kdb, VdT, out);
}